// Round 3
// baseline (301.290 us; speedup 1.0000x reference)
//
#include <hip/hip_runtime.h>
#include <stdint.h>

typedef unsigned long long u64;
typedef unsigned int u32;

#define N_ANCH     36864
#define PRE_NMS_N  6000
#define POST_NMS_N 300
#define NBINS      8192     // 13-bit score-prefix bins
#define GK_CAP     8192     // grouped-key capacity (bins<=B total; ~6005 expected)
#define NWORDS     94       // ceil(6000/64)

// ---- workspace layout (bytes) ----
#define OFF_BBOX   0                       // float4 bbox[36864]   589824
#define OFF_KEYS   589824                  // u64 keys[36864]      294912
#define OFF_GK     884736                  // u64 gkeys[8192]       65536
#define OFF_SBOX   950272                  // float4 sboxes[6000]   96000
#define OFF_META   1046272                 // u32 meta[8]              32
#define OFF_HIST   1046304                 // u32 hist[8192]        32768
#define OFF_CNT    1079072                 // u32 cnt[8192]         32768
#define OFF_OFFS   1111840                 // u32 offs[8193]        32772->32776
#define OFF_IREM   1144616                 // u64 irem[94]            752
#define OFF_M      1145368                 // u64 M[6000*94]      4512000
#define WS_FULL    (OFF_M + (size_t)PRE_NMS_N * NWORDS * 8)
#define WS_SMALL   (OFF_M)

__device__ __forceinline__ u64 make_key(float s, u32 idx) {
    u32 u = __float_as_uint(s);
    u32 sortable = u ^ ((u >> 31) ? 0xFFFFFFFFu : 0x80000000u);
    u32 hi = ~sortable;                 // ascending key == descending score
    return ((u64)hi << 32) | (u64)idx;  // tie-break: ascending index (stable argsort)
}

// K1: decode + clip + valid + key build + bin histogram (hist pre-zeroed by memset)
__global__ void k_decode(const float4* __restrict__ anchors,
                         const float* __restrict__ cls,
                         const float4* __restrict__ reg,
                         const int* __restrict__ img_w,
                         const int* __restrict__ img_h,
                         float4* __restrict__ bbox,
                         u64* __restrict__ keys,
                         u32* __restrict__ hist) {
    int i = blockIdx.x * blockDim.x + threadIdx.x;
    if (i >= N_ANCH) return;

    float4 a = anchors[i];
    float4 r = reg[i];
    float w  = a.z - a.x, h = a.w - a.y;
    float cx = a.x + 0.5f * w, cy = a.y + 0.5f * h;
    float pcx = r.x * w + cx, pcy = r.y * h + cy;
    float pw = expf(r.z) * w,  ph = expf(r.w) * h;
    float b0 = pcx - 0.5f * pw, b1 = pcy - 0.5f * ph;
    float b2 = pcx + 0.5f * pw, b3 = pcy + 0.5f * ph;

    float fh = (float)img_h[0], fw = (float)img_w[0];
    // reference: cols 0,2 clipped to [0, img_h]; cols 1,3 to [0, img_w]
    b0 = fminf(fmaxf(b0, 0.0f), fh);
    b2 = fminf(fmaxf(b2, 0.0f), fh);
    b1 = fminf(fmaxf(b1, 0.0f), fw);
    b3 = fminf(fmaxf(b3, 0.0f), fw);

    bool valid = (b2 - b0 >= 16.0f) && (b3 - b1 >= 16.0f);
    float score = valid ? cls[i] : -1e9f;

    bbox[i] = make_float4(b0, b1, b2, b3);
    u64 k = make_key(score, (u32)i);
    keys[i] = k;
    atomicAdd(&hist[(u32)(k >> 51)], 1u);
}

// K2: single-block prefix sum over 8192 bins -> exclusive offsets; find boundary
// bin B (count(bin<B) < 6000 <= count(bin<=B)); zero cnt; init irem to all-removed.
__global__ __launch_bounds__(1024) void k_scan(const u32* __restrict__ hist,
                                               u32* __restrict__ offs,
                                               u32* __restrict__ cnt,
                                               u64* __restrict__ irem,
                                               u32* __restrict__ meta) {
    __shared__ u32 psum[1024];
    int tid = threadIdx.x;
    for (int b = tid; b < NBINS; b += 1024) cnt[b] = 0u;
    if (tid < NWORDS) irem[tid] = ~0ull;

    u32 loc[8]; u32 s = 0;
    int base = tid * 8;
#pragma unroll
    for (int t = 0; t < 8; ++t) { loc[t] = hist[base + t]; s += loc[t]; }
    psum[tid] = s;
    __syncthreads();
    for (int off = 1; off < 1024; off <<= 1) {
        u32 v = (tid >= off) ? psum[tid - off] : 0u;
        __syncthreads();
        psum[tid] += v;
        __syncthreads();
    }
    u32 incl = psum[tid];
    u32 excl = incl - s;

    u32 run = excl;
#pragma unroll
    for (int t = 0; t < 8; ++t) { offs[base + t] = run; run += loc[t]; }
    if (tid == 1023) offs[NBINS] = incl;

    if (excl < (u32)PRE_NMS_N && incl >= (u32)PRE_NMS_N) {
        u32 c = excl;
#pragma unroll
        for (int t = 0; t < 8; ++t) {
            if (c + loc[t] >= (u32)PRE_NMS_N) {
                meta[1] = (u32)(base + t);   // boundary bin B
                meta[3] = c + loc[t];        // M = total keys in bins <= B
                break;
            }
            c += loc[t];
        }
    }
}

// K3: group keys of bins <= B into contiguous per-bin segments (unordered within bin)
__global__ void k_scatter(const u64* __restrict__ keys,
                          const u32* __restrict__ offs,
                          u32* __restrict__ cnt,
                          u64* __restrict__ gkeys,
                          const u32* __restrict__ meta) {
    int i = blockIdx.x * blockDim.x + threadIdx.x;
    if (i >= N_ANCH) return;
    u32 B = meta[1];
    u64 k = keys[i];
    u32 bin = (u32)(k >> 51);
    if (bin <= B) {
        u32 p = offs[bin] + atomicAdd(&cnt[bin], 1u);
        if (p < GK_CAP) gkeys[p] = k;
    }
}

// K4: exact sorted rank = bin offset + #(smaller keys within own bin segment).
// Scatter top-6000 boxes into sboxes[rank]; clear irem bit for valid boxes.
__global__ void k_rank(const u64* __restrict__ gkeys,
                       const u32* __restrict__ offs,
                       const float4* __restrict__ bbox,
                       float4* __restrict__ sboxes,
                       u64* __restrict__ irem,
                       const u32* __restrict__ meta) {
    int s = blockIdx.x * blockDim.x + threadIdx.x;
    u32 M = meta[3];
    if (M > GK_CAP) M = GK_CAP;
    if (s >= (int)M) return;
    u64 k = gkeys[s];
    u32 bin = (u32)(k >> 51);
    u32 st = offs[bin], en = offs[bin + 1];
    if (en > GK_CAP) en = GK_CAP;
    u32 r = st;
    for (u32 t = st; t < en; ++t) r += (gkeys[t] < k) ? 1u : 0u;
    if (r < (u32)PRE_NMS_N) {
        u32 idx = (u32)k;
        float4 b = bbox[idx];
        sboxes[r] = b;
        bool valid = (b.z - b.x >= 16.0f) && (b.w - b.y >= 16.0f);
        if (valid) atomicAnd(&irem[r >> 6], ~(1ull << (r & 63)));
    }
}

// K5a: suppression bitmask matrix. Block = 16 waves; wave w computes row
// i = blockIdx*16+w against all 6000 boxes staged in LDS.
__global__ __launch_bounds__(1024) void k_iou(const float4* __restrict__ sboxes,
                                              u64* __restrict__ M) {
    __shared__ float4 sb[PRE_NMS_N];   // 96000 B
    int tid = threadIdx.x, lane = tid & 63, wave = tid >> 6;
    for (int r = tid; r < PRE_NMS_N; r += 1024) sb[r] = sboxes[r];
    __syncthreads();

    int i = blockIdx.x * 16 + wave;    // grid = 375 -> i in [0,6000)
    float4 bi = sb[i];
    float ai = (bi.z - bi.x) * (bi.w - bi.y);
    int w0 = i >> 6;
    u64* row = M + (size_t)i * NWORDS;
    for (int w = 0; w < NWORDS; ++w) {
        u64 m = 0;
        if (w >= w0) {
            int j = (w << 6) + lane;
            bool sup = false;
            if (j > i && j < PRE_NMS_N) {
                float4 bj = sb[j];
                float aj = (bj.z - bj.x) * (bj.w - bj.y);
                float xx1 = fmaxf(bi.x, bj.x), yy1 = fmaxf(bi.y, bj.y);
                float xx2 = fminf(bi.z, bj.z), yy2 = fminf(bi.w, bj.w);
                float inter = fmaxf(xx2 - xx1, 0.0f) * fmaxf(yy2 - yy1, 0.0f);
                float iou = inter / (ai + aj - inter + 1e-9f);  // EXACT ref arithmetic
                sup = iou > 0.7f;
            }
            m = __ballot(sup);
        }
        if (lane == 0) row[w] = m;
    }
}

// K5b: single-wave serial greedy reduce over precomputed rows.
// removed mask lives in 2 u64 registers per lane (94 words across 64 lanes).
__global__ __launch_bounds__(64) void k_reduce(const float4* __restrict__ sboxes,
                                               const u64* __restrict__ M,
                                               const u64* __restrict__ irem,
                                               float* __restrict__ out) {
    __shared__ int kept[POST_NMS_N];
    int lane = threadIdx.x;
    u64 rem0 = irem[lane];
    u64 rem1 = (lane < NWORDS - 64) ? irem[64 + lane] : ~0ull;
    int w1idx = (lane < NWORDS - 64) ? (64 + lane) : (NWORDS - 1);
    int kc = 0;
    bool done = false;

    u64 a0[8], a1[8], b0[8], b1[8];

#define LOAD_BATCH(R0, R1, BASE)                                       \
    {                                                                  \
        _Pragma("unroll")                                              \
        for (int t = 0; t < 8; ++t) {                                  \
            int q = (BASE) + t;                                        \
            q = q < PRE_NMS_N ? q : (PRE_NMS_N - 1);                   \
            const u64* rp = M + (size_t)q * NWORDS;                    \
            R0[t] = rp[lane];                                          \
            R1[t] = rp[w1idx];                                         \
        }                                                              \
    }

#define PROC_BATCH(R0, R1, BASE)                                       \
    {                                                                  \
        _Pragma("unroll")                                              \
        for (int t = 0; t < 8; ++t) {                                  \
            int q = (BASE) + t;                                        \
            if (!done && q < PRE_NMS_N) {                              \
                int owner = q >> 6;                                    \
                u64 wsel = (owner < 64) ? __shfl(rem0, owner)          \
                                        : __shfl(rem1, owner - 64);    \
                if (!((wsel >> (q & 63)) & 1ull)) {                    \
                    if (lane == 0) kept[kc] = q;                       \
                    ++kc;                                              \
                    rem0 |= R0[t];                                     \
                    rem1 |= R1[t];                                     \
                    if (kc >= POST_NMS_N) done = true;                 \
                }                                                      \
            }                                                          \
        }                                                              \
    }

    LOAD_BATCH(a0, a1, 0);
    for (int base = 0; base < PRE_NMS_N; base += 16) {
        LOAD_BATCH(b0, b1, base + 8);
        PROC_BATCH(a0, a1, base);
        if (done) break;
        LOAD_BATCH(a0, a1, base + 16);
        PROC_BATCH(b0, b1, base + 8);
        if (done) break;
    }
#undef LOAD_BATCH
#undef PROC_BATCH

    for (int r = lane; r < POST_NMS_N; r += 64) {
        float4 v = make_float4(0.0f, 0.0f, 0.0f, 0.0f);
        if (r < kc) v = sboxes[kept[r]];
        ((float4*)out)[r] = v;
    }
}

// Fallback NMS (single fused kernel) if ws_size can't hold the bitmask matrix.
__global__ void k_nms(const float4* __restrict__ sboxes, float* __restrict__ out) {
    __shared__ float4 boxes[PRE_NMS_N];
    __shared__ u64 removed[NWORDS];
    __shared__ int kept[POST_NMS_N];
    int tid = threadIdx.x;
    int lane = tid & 63, wave = tid >> 6;

    for (int r = tid; r < PRE_NMS_N; r += 1024) boxes[r] = sboxes[r];
    __syncthreads();
    for (int r = tid; r < NWORDS * 64; r += 1024) {
        bool rm = true;
        if (r < PRE_NMS_N) {
            float4 b = boxes[r];
            rm = !((b.z - b.x >= 16.0f) && (b.w - b.y >= 16.0f));
        }
        u64 m = __ballot(rm);
        if (lane == 0) removed[r >> 6] = m;
    }
    __syncthreads();

    int kc = 0;
    int i = 0;
    while (i < PRE_NMS_N) {
        int w = i >> 6;
        u64 wd = removed[w] | ((1ull << (i & 63)) - 1ull);
        while (wd == ~0ull) {
            ++w;
            if (w >= NWORDS) break;
            wd = removed[w];
        }
        if (w >= NWORDS) break;
        i = (w << 6) + (__ffsll((u64)(~wd)) - 1);
        if (i >= PRE_NMS_N) break;

        if (tid == 0) kept[kc] = i;
        ++kc;
        if (kc >= POST_NMS_N) break;

        float4 bi = boxes[i];
        float area_i = (bi.z - bi.x) * (bi.w - bi.y);
        for (int c = (i >> 6) + wave; c < NWORDS; c += 16) {
            int j = (c << 6) + lane;
            bool sup = false;
            if (j > i && j < PRE_NMS_N) {
                float4 bj = boxes[j];
                float area_j = (bj.z - bj.x) * (bj.w - bj.y);
                float xx1 = fmaxf(bi.x, bj.x), yy1 = fmaxf(bi.y, bj.y);
                float xx2 = fminf(bi.z, bj.z), yy2 = fminf(bi.w, bj.w);
                float iw = fmaxf(xx2 - xx1, 0.0f), ih = fmaxf(yy2 - yy1, 0.0f);
                float inter = iw * ih;
                float iou = inter / (area_i + area_j - inter + 1e-9f);
                sup = iou > 0.7f;
            }
            u64 m = __ballot(sup);
            if (lane == 0 && m) removed[c] |= m;
        }
        __syncthreads();
        ++i;
    }
    __syncthreads();

    for (int r = tid; r < POST_NMS_N; r += 1024) {
        float4 v = make_float4(0.0f, 0.0f, 0.0f, 0.0f);
        if (r < kc) v = boxes[kept[r]];
        ((float4*)out)[r] = v;
    }
}

extern "C" void kernel_launch(void* const* d_in, const int* in_sizes, int n_in,
                              void* d_out, int out_size, void* d_ws, size_t ws_size,
                              hipStream_t stream) {
    const float4* anchors = (const float4*)d_in[0];
    const float*  cls     = (const float*)d_in[1];
    const float4* reg     = (const float4*)d_in[2];
    const int*    img_w   = (const int*)d_in[3];
    const int*    img_h   = (const int*)d_in[4];

    char* ws = (char*)d_ws;
    float4* bbox   = (float4*)(ws + OFF_BBOX);
    u64*    keys   = (u64*)   (ws + OFF_KEYS);
    u64*    gkeys  = (u64*)   (ws + OFF_GK);
    float4* sboxes = (float4*)(ws + OFF_SBOX);
    u32*    meta   = (u32*)   (ws + OFF_META);
    u32*    hist   = (u32*)   (ws + OFF_HIST);
    u32*    cnt    = (u32*)   (ws + OFF_CNT);
    u32*    offs   = (u32*)   (ws + OFF_OFFS);
    u64*    irem   = (u64*)   (ws + OFF_IREM);
    u64*    M      = (u64*)   (ws + OFF_M);

    hipMemsetAsync(hist, 0, NBINS * sizeof(u32), stream);

    k_decode <<<dim3((N_ANCH + 255) / 256), dim3(256), 0, stream>>>(
        anchors, cls, reg, img_w, img_h, bbox, keys, hist);
    k_scan   <<<dim3(1), dim3(1024), 0, stream>>>(hist, offs, cnt, irem, meta);
    k_scatter<<<dim3((N_ANCH + 255) / 256), dim3(256), 0, stream>>>(
        keys, offs, cnt, gkeys, meta);
    k_rank   <<<dim3(GK_CAP / 256), dim3(256), 0, stream>>>(
        gkeys, offs, bbox, sboxes, irem, meta);

    if (ws_size >= WS_FULL) {
        k_iou    <<<dim3(PRE_NMS_N / 16), dim3(1024), 0, stream>>>(sboxes, M);
        k_reduce <<<dim3(1), dim3(64), 0, stream>>>(sboxes, M, irem, (float*)d_out);
    } else {
        k_nms    <<<dim3(1), dim3(1024), 0, stream>>>(sboxes, (float*)d_out);
    }
}

// Round 4
// 117.659 us; speedup vs baseline: 2.5607x; 2.5607x over previous
//
#include <hip/hip_runtime.h>
#include <stdint.h>

typedef unsigned long long u64;
typedef unsigned int u32;

#define N_ANCH     36864
#define PRE_NMS_N  6000
#define POST_NMS_N 300
#define NBINS      8192     // value-uniform score bins
#define GK_CAP     8192     // grouped-key capacity (bins<=B total; ~6005 expected)
#define NWORDS     94       // ceil(6000/64)

// ---- workspace layout (bytes) ----
#define OFF_BBOX   0                       // float4 bbox[36864]   589824
#define OFF_KEYS   589824                  // u64 keys[36864]      294912
#define OFF_GK     884736                  // u64 gkeys[8192]       65536
#define OFF_SBOX   950272                  // float4 sboxes[6000]   96000
#define OFF_META   1046272                 // u32 meta[8]              32
#define OFF_HIST   1046304                 // u32 hist[8192]        32768
#define OFF_CNT    1079072                 // u32 cnt[8192]         32768
#define OFF_OFFS   1111840                 // u32 offs[8193]        32776
#define OFF_IREM   1144616                 // u64 irem[94]            752
#define OFF_M      1145368                 // u64 M[6000*94]      4512000
#define WS_FULL    (OFF_M + (size_t)PRE_NMS_N * NWORDS * 8)

// Value-uniform monotone bin: higher score -> lower bin. Uniform scores in
// [0,1) spread evenly (~4.5 keys/bin), unlike float-bit prefixes where half
// the mass ([0.5,1.0), one exponent) collapses into 16 bins.
__device__ __forceinline__ u32 score_bin(float s) {
    float v = fminf(fmaxf(s, 0.0f), 1.0f);
    u32 q = (u32)(v * 8192.0f);
    if (q > 8191u) q = 8191u;
    return 8191u - q;
}

// key = bin(16) | sortable_score(32) | idx(16); ascending u64 order
// == (score desc, idx asc) exactly (bin is monotone in score).
__device__ __forceinline__ u64 make_key(float s, u32 bin, u32 idx) {
    u32 u = __float_as_uint(s);
    u32 sortable = u ^ ((u >> 31) ? 0xFFFFFFFFu : 0x80000000u);
    u32 hi = ~sortable;                 // ascending == descending score
    return ((u64)bin << 48) | ((u64)hi << 16) | (u64)idx;
}

// K1: decode + clip + valid + key build + bin histogram (hist pre-zeroed by memset)
__global__ void k_decode(const float4* __restrict__ anchors,
                         const float* __restrict__ cls,
                         const float4* __restrict__ reg,
                         const int* __restrict__ img_w,
                         const int* __restrict__ img_h,
                         float4* __restrict__ bbox,
                         u64* __restrict__ keys,
                         u32* __restrict__ hist) {
    int i = blockIdx.x * blockDim.x + threadIdx.x;
    if (i >= N_ANCH) return;

    float4 a = anchors[i];
    float4 r = reg[i];
    float w  = a.z - a.x, h = a.w - a.y;
    float cx = a.x + 0.5f * w, cy = a.y + 0.5f * h;
    float pcx = r.x * w + cx, pcy = r.y * h + cy;
    float pw = expf(r.z) * w,  ph = expf(r.w) * h;
    float b0 = pcx - 0.5f * pw, b1 = pcy - 0.5f * ph;
    float b2 = pcx + 0.5f * pw, b3 = pcy + 0.5f * ph;

    float fh = (float)img_h[0], fw = (float)img_w[0];
    // reference: cols 0,2 clipped to [0, img_h]; cols 1,3 to [0, img_w]
    b0 = fminf(fmaxf(b0, 0.0f), fh);
    b2 = fminf(fmaxf(b2, 0.0f), fh);
    b1 = fminf(fmaxf(b1, 0.0f), fw);
    b3 = fminf(fmaxf(b3, 0.0f), fw);

    bool valid = (b2 - b0 >= 16.0f) && (b3 - b1 >= 16.0f);
    float score = valid ? cls[i] : -1e9f;

    bbox[i] = make_float4(b0, b1, b2, b3);
    u32 bin = score_bin(score);
    keys[i] = make_key(score, bin, (u32)i);
    atomicAdd(&hist[bin], 1u);
}

// K2: single-block prefix sum over 8192 bins -> exclusive offsets; find boundary
// bin B (count(bin<B) < 6000 <= count(bin<=B)); zero cnt; init irem all-removed.
__global__ __launch_bounds__(1024) void k_scan(const u32* __restrict__ hist,
                                               u32* __restrict__ offs,
                                               u32* __restrict__ cnt,
                                               u64* __restrict__ irem,
                                               u32* __restrict__ meta) {
    __shared__ u32 psum[1024];
    int tid = threadIdx.x;
    for (int b = tid; b < NBINS; b += 1024) cnt[b] = 0u;
    if (tid < NWORDS) irem[tid] = ~0ull;

    u32 loc[8]; u32 s = 0;
    int base = tid * 8;
#pragma unroll
    for (int t = 0; t < 8; ++t) { loc[t] = hist[base + t]; s += loc[t]; }
    psum[tid] = s;
    __syncthreads();
    for (int off = 1; off < 1024; off <<= 1) {
        u32 v = (tid >= off) ? psum[tid - off] : 0u;
        __syncthreads();
        psum[tid] += v;
        __syncthreads();
    }
    u32 incl = psum[tid];
    u32 excl = incl - s;

    u32 run = excl;
#pragma unroll
    for (int t = 0; t < 8; ++t) { offs[base + t] = run; run += loc[t]; }
    if (tid == 1023) offs[NBINS] = incl;

    if (excl < (u32)PRE_NMS_N && incl >= (u32)PRE_NMS_N) {
        u32 c = excl;
#pragma unroll
        for (int t = 0; t < 8; ++t) {
            if (c + loc[t] >= (u32)PRE_NMS_N) {
                meta[1] = (u32)(base + t);   // boundary bin B
                meta[3] = c + loc[t];        // M = total keys in bins <= B
                break;
            }
            c += loc[t];
        }
    }
}

// K3: group keys of bins <= B into contiguous per-bin segments (unordered within bin)
__global__ void k_scatter(const u64* __restrict__ keys,
                          const u32* __restrict__ offs,
                          u32* __restrict__ cnt,
                          u64* __restrict__ gkeys,
                          const u32* __restrict__ meta) {
    int i = blockIdx.x * blockDim.x + threadIdx.x;
    if (i >= N_ANCH) return;
    u32 B = meta[1];
    u64 k = keys[i];
    u32 bin = (u32)(k >> 48);
    if (bin <= B) {
        u32 p = offs[bin] + atomicAdd(&cnt[bin], 1u);
        if (p < GK_CAP) gkeys[p] = k;
    }
}

// K4: exact sorted rank = bin offset + #(smaller keys within own bin segment).
// Scatter top-6000 boxes into sboxes[rank]; clear irem bit for valid boxes.
__global__ void k_rank(const u64* __restrict__ gkeys,
                       const u32* __restrict__ offs,
                       const float4* __restrict__ bbox,
                       float4* __restrict__ sboxes,
                       u64* __restrict__ irem,
                       const u32* __restrict__ meta) {
    int s = blockIdx.x * blockDim.x + threadIdx.x;
    u32 M = meta[3];
    if (M > GK_CAP) M = GK_CAP;
    if (s >= (int)M) return;
    u64 k = gkeys[s];
    u32 bin = (u32)(k >> 48);
    u32 st = offs[bin], en = offs[bin + 1];
    if (en > GK_CAP) en = GK_CAP;
    u32 r = st;
    for (u32 t = st; t < en; ++t) r += (gkeys[t] < k) ? 1u : 0u;
    if (r < (u32)PRE_NMS_N) {
        u32 idx = (u32)(k & 0xFFFFu);
        float4 b = bbox[idx];
        sboxes[r] = b;
        bool valid = (b.z - b.x >= 16.0f) && (b.w - b.y >= 16.0f);
        if (valid) atomicAnd(&irem[r >> 6], ~(1ull << (r & 63)));
    }
}

// K5a: suppression bitmask matrix. Block = 16 waves; wave w computes row
// i = blockIdx*16+w against all 6000 boxes staged in LDS.
__global__ __launch_bounds__(1024) void k_iou(const float4* __restrict__ sboxes,
                                              u64* __restrict__ M) {
    __shared__ float4 sb[PRE_NMS_N];   // 96000 B
    int tid = threadIdx.x, lane = tid & 63, wave = tid >> 6;
    for (int r = tid; r < PRE_NMS_N; r += 1024) sb[r] = sboxes[r];
    __syncthreads();

    int i = blockIdx.x * 16 + wave;    // grid = 375 -> i in [0,6000)
    float4 bi = sb[i];
    float ai = (bi.z - bi.x) * (bi.w - bi.y);
    int w0 = i >> 6;
    u64* row = M + (size_t)i * NWORDS;
    for (int w = 0; w < NWORDS; ++w) {
        u64 m = 0;
        if (w >= w0) {
            int j = (w << 6) + lane;
            bool sup = false;
            if (j > i && j < PRE_NMS_N) {
                float4 bj = sb[j];
                float aj = (bj.z - bj.x) * (bj.w - bj.y);
                float xx1 = fmaxf(bi.x, bj.x), yy1 = fmaxf(bi.y, bj.y);
                float xx2 = fminf(bi.z, bj.z), yy2 = fminf(bi.w, bj.w);
                float inter = fmaxf(xx2 - xx1, 0.0f) * fmaxf(yy2 - yy1, 0.0f);
                float iou = inter / (ai + aj - inter + 1e-9f);  // EXACT ref arithmetic
                sup = iou > 0.7f;
            }
            m = __ballot(sup);
        }
        if (lane == 0) row[w] = m;
    }
}

// K5b: single-wave serial greedy reduce over precomputed rows.
// removed mask lives in 2 u64 registers per lane (94 words across 64 lanes).
__global__ __launch_bounds__(64) void k_reduce(const float4* __restrict__ sboxes,
                                               const u64* __restrict__ M,
                                               const u64* __restrict__ irem,
                                               float* __restrict__ out) {
    __shared__ int kept[POST_NMS_N];
    int lane = threadIdx.x;
    u64 rem0 = irem[lane];
    u64 rem1 = (lane < NWORDS - 64) ? irem[64 + lane] : ~0ull;
    int w1idx = (lane < NWORDS - 64) ? (64 + lane) : (NWORDS - 1);
    int kc = 0;
    bool done = false;

    u64 a0[8], a1[8], b0[8], b1[8];

#define LOAD_BATCH(R0, R1, BASE)                                       \
    {                                                                  \
        _Pragma("unroll")                                              \
        for (int t = 0; t < 8; ++t) {                                  \
            int q = (BASE) + t;                                        \
            q = q < PRE_NMS_N ? q : (PRE_NMS_N - 1);                   \
            const u64* rp = M + (size_t)q * NWORDS;                    \
            R0[t] = rp[lane];                                          \
            R1[t] = rp[w1idx];                                         \
        }                                                              \
    }

#define PROC_BATCH(R0, R1, BASE)                                       \
    {                                                                  \
        _Pragma("unroll")                                              \
        for (int t = 0; t < 8; ++t) {                                  \
            int q = (BASE) + t;                                        \
            if (!done && q < PRE_NMS_N) {                              \
                int owner = q >> 6;                                    \
                u64 wsel = (owner < 64) ? __shfl(rem0, owner)          \
                                        : __shfl(rem1, owner - 64);    \
                if (!((wsel >> (q & 63)) & 1ull)) {                    \
                    if (lane == 0) kept[kc] = q;                       \
                    ++kc;                                              \
                    rem0 |= R0[t];                                     \
                    rem1 |= R1[t];                                     \
                    if (kc >= POST_NMS_N) done = true;                 \
                }                                                      \
            }                                                          \
        }                                                              \
    }

    LOAD_BATCH(a0, a1, 0);
    for (int base = 0; base < PRE_NMS_N; base += 16) {
        LOAD_BATCH(b0, b1, base + 8);
        PROC_BATCH(a0, a1, base);
        if (done) break;
        LOAD_BATCH(a0, a1, base + 16);
        PROC_BATCH(b0, b1, base + 8);
        if (done) break;
    }
#undef LOAD_BATCH
#undef PROC_BATCH

    for (int r = lane; r < POST_NMS_N; r += 64) {
        float4 v = make_float4(0.0f, 0.0f, 0.0f, 0.0f);
        if (r < kc) v = sboxes[kept[r]];
        ((float4*)out)[r] = v;
    }
}

// Fallback NMS (single fused kernel) if ws_size can't hold the bitmask matrix.
__global__ void k_nms(const float4* __restrict__ sboxes, float* __restrict__ out) {
    __shared__ float4 boxes[PRE_NMS_N];
    __shared__ u64 removed[NWORDS];
    __shared__ int kept[POST_NMS_N];
    int tid = threadIdx.x;
    int lane = tid & 63, wave = tid >> 6;

    for (int r = tid; r < PRE_NMS_N; r += 1024) boxes[r] = sboxes[r];
    __syncthreads();
    for (int r = tid; r < NWORDS * 64; r += 1024) {
        bool rm = true;
        if (r < PRE_NMS_N) {
            float4 b = boxes[r];
            rm = !((b.z - b.x >= 16.0f) && (b.w - b.y >= 16.0f));
        }
        u64 m = __ballot(rm);
        if (lane == 0) removed[r >> 6] = m;
    }
    __syncthreads();

    int kc = 0;
    int i = 0;
    while (i < PRE_NMS_N) {
        int w = i >> 6;
        u64 wd = removed[w] | ((1ull << (i & 63)) - 1ull);
        while (wd == ~0ull) {
            ++w;
            if (w >= NWORDS) break;
            wd = removed[w];
        }
        if (w >= NWORDS) break;
        i = (w << 6) + (__ffsll((u64)(~wd)) - 1);
        if (i >= PRE_NMS_N) break;

        if (tid == 0) kept[kc] = i;
        ++kc;
        if (kc >= POST_NMS_N) break;

        float4 bi = boxes[i];
        float area_i = (bi.z - bi.x) * (bi.w - bi.y);
        for (int c = (i >> 6) + wave; c < NWORDS; c += 16) {
            int j = (c << 6) + lane;
            bool sup = false;
            if (j > i && j < PRE_NMS_N) {
                float4 bj = boxes[j];
                float area_j = (bj.z - bj.x) * (bj.w - bj.y);
                float xx1 = fmaxf(bi.x, bj.x), yy1 = fmaxf(bi.y, bj.y);
                float xx2 = fminf(bi.z, bj.z), yy2 = fminf(bi.w, bj.w);
                float iw = fmaxf(xx2 - xx1, 0.0f), ih = fmaxf(yy2 - yy1, 0.0f);
                float inter = iw * ih;
                float iou = inter / (area_i + area_j - inter + 1e-9f);
                sup = iou > 0.7f;
            }
            u64 m = __ballot(sup);
            if (lane == 0 && m) removed[c] |= m;
        }
        __syncthreads();
        ++i;
    }
    __syncthreads();

    for (int r = tid; r < POST_NMS_N; r += 1024) {
        float4 v = make_float4(0.0f, 0.0f, 0.0f, 0.0f);
        if (r < kc) v = boxes[kept[r]];
        ((float4*)out)[r] = v;
    }
}

extern "C" void kernel_launch(void* const* d_in, const int* in_sizes, int n_in,
                              void* d_out, int out_size, void* d_ws, size_t ws_size,
                              hipStream_t stream) {
    const float4* anchors = (const float4*)d_in[0];
    const float*  cls     = (const float*)d_in[1];
    const float4* reg     = (const float4*)d_in[2];
    const int*    img_w   = (const int*)d_in[3];
    const int*    img_h   = (const int*)d_in[4];

    char* ws = (char*)d_ws;
    float4* bbox   = (float4*)(ws + OFF_BBOX);
    u64*    keys   = (u64*)   (ws + OFF_KEYS);
    u64*    gkeys  = (u64*)   (ws + OFF_GK);
    float4* sboxes = (float4*)(ws + OFF_SBOX);
    u32*    meta   = (u32*)   (ws + OFF_META);
    u32*    hist   = (u32*)   (ws + OFF_HIST);
    u32*    cnt    = (u32*)   (ws + OFF_CNT);
    u32*    offs   = (u32*)   (ws + OFF_OFFS);
    u64*    irem   = (u64*)   (ws + OFF_IREM);
    u64*    M      = (u64*)   (ws + OFF_M);

    hipMemsetAsync(hist, 0, NBINS * sizeof(u32), stream);

    k_decode <<<dim3((N_ANCH + 255) / 256), dim3(256), 0, stream>>>(
        anchors, cls, reg, img_w, img_h, bbox, keys, hist);
    k_scan   <<<dim3(1), dim3(1024), 0, stream>>>(hist, offs, cnt, irem, meta);
    k_scatter<<<dim3((N_ANCH + 255) / 256), dim3(256), 0, stream>>>(
        keys, offs, cnt, gkeys, meta);
    k_rank   <<<dim3(GK_CAP / 256), dim3(256), 0, stream>>>(
        gkeys, offs, bbox, sboxes, irem, meta);

    if (ws_size >= WS_FULL) {
        k_iou    <<<dim3(PRE_NMS_N / 16), dim3(1024), 0, stream>>>(sboxes, M);
        k_reduce <<<dim3(1), dim3(64), 0, stream>>>(sboxes, M, irem, (float*)d_out);
    } else {
        k_nms    <<<dim3(1), dim3(1024), 0, stream>>>(sboxes, (float*)d_out);
    }
}

// Round 5
// 115.687 us; speedup vs baseline: 2.6044x; 1.0170x over previous
//
#include <hip/hip_runtime.h>
#include <stdint.h>

typedef unsigned long long u64;
typedef unsigned int u32;

#define N_ANCH     36864
#define PRE_NMS_N  6000
#define POST_NMS_N 300
#define NBINS      8192     // value-uniform score bins
#define GK_CAP     8192     // grouped-key capacity (bins<=B total; ~6005 expected)
#define NWORDS     94       // ceil(6000/64)

// ---- workspace layout (bytes) ----
#define OFF_BBOX   0                       // float4 bbox[36864]   589824
#define OFF_KEYS   589824                  // u64 keys[36864]      294912
#define OFF_GK     884736                  // u64 gkeys[8192]       65536
#define OFF_SBOX   950272                  // float4 sboxes[6000]   96000
#define OFF_META   1046272                 // u32 meta[8]              32
#define OFF_CNT    1046304                 // u32 cnt[8192]         32768
#define OFF_OFFS   1079072                 // u32 offs[8193]        32776
#define OFF_IREM   1111848                 // u64 irem[94]            752
#define OFF_M      1112600                 // u64 M[6000*94]      4512000
#define WS_FULL    (OFF_M + (size_t)PRE_NMS_N * NWORDS * 8)

// Value-uniform monotone bin: higher score -> lower bin. Uniform scores spread
// evenly (~4.5 keys/bin); float-bit prefixes would collapse [0.5,1) into 16 bins.
__device__ __forceinline__ u32 score_bin(float s) {
    float v = fminf(fmaxf(s, 0.0f), 1.0f);
    u32 q = (u32)(v * 8192.0f);
    if (q > 8191u) q = 8191u;
    return 8191u - q;
}

// key = bin(16) | sortable_score(32) | idx(16); ascending u64 order
// == (score desc, idx asc) exactly (bin is monotone in score).
__device__ __forceinline__ u64 make_key(float s, u32 bin, u32 idx) {
    u32 u = __float_as_uint(s);
    u32 sortable = u ^ ((u >> 31) ? 0xFFFFFFFFu : 0x80000000u);
    u32 hi = ~sortable;                 // ascending == descending score
    return ((u64)bin << 48) | ((u64)hi << 16) | (u64)idx;
}

__device__ __forceinline__ u64 readlane_u64(u64 v, int l) {
    u32 lo = __builtin_amdgcn_readlane((u32)(v & 0xFFFFFFFFull), l);
    u32 hi = __builtin_amdgcn_readlane((u32)(v >> 32), l);
    return ((u64)hi << 32) | (u64)lo;
}

// K1: decode + clip + valid + key build
__global__ void k_decode(const float4* __restrict__ anchors,
                         const float* __restrict__ cls,
                         const float4* __restrict__ reg,
                         const int* __restrict__ img_w,
                         const int* __restrict__ img_h,
                         float4* __restrict__ bbox,
                         u64* __restrict__ keys) {
    int i = blockIdx.x * blockDim.x + threadIdx.x;
    if (i >= N_ANCH) return;

    float4 a = anchors[i];
    float4 r = reg[i];
    float w  = a.z - a.x, h = a.w - a.y;
    float cx = a.x + 0.5f * w, cy = a.y + 0.5f * h;
    float pcx = r.x * w + cx, pcy = r.y * h + cy;
    float pw = expf(r.z) * w,  ph = expf(r.w) * h;
    float b0 = pcx - 0.5f * pw, b1 = pcy - 0.5f * ph;
    float b2 = pcx + 0.5f * pw, b3 = pcy + 0.5f * ph;

    float fh = (float)img_h[0], fw = (float)img_w[0];
    // reference: cols 0,2 clipped to [0, img_h]; cols 1,3 to [0, img_w]
    b0 = fminf(fmaxf(b0, 0.0f), fh);
    b2 = fminf(fmaxf(b2, 0.0f), fh);
    b1 = fminf(fmaxf(b1, 0.0f), fw);
    b3 = fminf(fmaxf(b3, 0.0f), fw);

    bool valid = (b2 - b0 >= 16.0f) && (b3 - b1 >= 16.0f);
    float score = valid ? cls[i] : -1e9f;

    bbox[i] = make_float4(b0, b1, b2, b3);
    keys[i] = make_key(score, score_bin(score), (u32)i);
}

// K2: build 8192-bin histogram in LDS from keys, prefix-sum -> offsets, find
// boundary bin B (count(bin<B) < 6000 <= count(bin<=B)); zero cnt; init irem.
__global__ __launch_bounds__(1024) void k_scan(const u64* __restrict__ keys,
                                               u32* __restrict__ offs,
                                               u32* __restrict__ cnt,
                                               u64* __restrict__ irem,
                                               u32* __restrict__ meta) {
    __shared__ u32 hist[NBINS];   // 32 KiB
    __shared__ u32 psum[1024];
    int tid = threadIdx.x;
    for (int b = tid; b < NBINS; b += 1024) { hist[b] = 0u; cnt[b] = 0u; }
    if (tid < NWORDS) irem[tid] = ~0ull;
    __syncthreads();
    for (int i = tid; i < N_ANCH; i += 1024)
        atomicAdd(&hist[(u32)(keys[i] >> 48)], 1u);
    __syncthreads();

    u32 loc[8]; u32 s = 0;
    int base = tid * 8;
#pragma unroll
    for (int t = 0; t < 8; ++t) { loc[t] = hist[base + t]; s += loc[t]; }
    psum[tid] = s;
    __syncthreads();
    for (int off = 1; off < 1024; off <<= 1) {
        u32 v = (tid >= off) ? psum[tid - off] : 0u;
        __syncthreads();
        psum[tid] += v;
        __syncthreads();
    }
    u32 incl = psum[tid];
    u32 excl = incl - s;

    u32 run = excl;
#pragma unroll
    for (int t = 0; t < 8; ++t) { offs[base + t] = run; run += loc[t]; }
    if (tid == 1023) offs[NBINS] = incl;

    if (excl < (u32)PRE_NMS_N && incl >= (u32)PRE_NMS_N) {
        u32 c = excl;
#pragma unroll
        for (int t = 0; t < 8; ++t) {
            if (c + loc[t] >= (u32)PRE_NMS_N) {
                meta[1] = (u32)(base + t);   // boundary bin B
                meta[3] = c + loc[t];        // M = total keys in bins <= B
                break;
            }
            c += loc[t];
        }
    }
}

// K3: group keys of bins <= B into contiguous per-bin segments
__global__ void k_scatter(const u64* __restrict__ keys,
                          const u32* __restrict__ offs,
                          u32* __restrict__ cnt,
                          u64* __restrict__ gkeys,
                          const u32* __restrict__ meta) {
    int i = blockIdx.x * blockDim.x + threadIdx.x;
    if (i >= N_ANCH) return;
    u32 B = meta[1];
    u64 k = keys[i];
    u32 bin = (u32)(k >> 48);
    if (bin <= B) {
        u32 p = offs[bin] + atomicAdd(&cnt[bin], 1u);
        if (p < GK_CAP) gkeys[p] = k;
    }
}

// K4: exact rank = bin offset + #(smaller keys in own bin segment); scatter
// top-6000 boxes into sboxes[rank]; clear irem bit for valid boxes.
__global__ void k_rank(const u64* __restrict__ gkeys,
                       const u32* __restrict__ offs,
                       const float4* __restrict__ bbox,
                       float4* __restrict__ sboxes,
                       u64* __restrict__ irem,
                       const u32* __restrict__ meta) {
    int s = blockIdx.x * blockDim.x + threadIdx.x;
    u32 M = meta[3];
    if (M > GK_CAP) M = GK_CAP;
    if (s >= (int)M) return;
    u64 k = gkeys[s];
    u32 bin = (u32)(k >> 48);
    u32 st = offs[bin], en = offs[bin + 1];
    if (en > GK_CAP) en = GK_CAP;
    u32 r = st;
    for (u32 t = st; t < en; ++t) r += (gkeys[t] < k) ? 1u : 0u;
    if (r < (u32)PRE_NMS_N) {
        u32 idx = (u32)(k & 0xFFFFu);
        float4 b = bbox[idx];
        sboxes[r] = b;
        bool valid = (b.z - b.x >= 16.0f) && (b.w - b.y >= 16.0f);
        if (valid) atomicAnd(&irem[r >> 6], ~(1ull << (r & 63)));
    }
}

// K5a: suppression bitmask matrix, TRIANGULAR: row i only writes words >= i>>6.
// Words < i>>6 stay garbage (0xAA poison) -> k_reduce masks them out.
__global__ __launch_bounds__(1024) void k_iou(const float4* __restrict__ sboxes,
                                              u64* __restrict__ M) {
    __shared__ float4 sb[PRE_NMS_N];   // 96000 B
    int tid = threadIdx.x, lane = tid & 63, wave = tid >> 6;
    for (int r = tid; r < PRE_NMS_N; r += 1024) sb[r] = sboxes[r];
    __syncthreads();

    int i = blockIdx.x * 16 + wave;    // grid = 375 -> i in [0,6000)
    float4 bi = sb[i];
    float ai = (bi.z - bi.x) * (bi.w - bi.y);
    int w0 = i >> 6;
    u64* row = M + (size_t)i * NWORDS;
    for (int w = w0; w < NWORDS; ++w) {
        int j = (w << 6) + lane;
        bool sup = false;
        if (j > i && j < PRE_NMS_N) {
            float4 bj = sb[j];
            float aj = (bj.z - bj.x) * (bj.w - bj.y);
            float xx1 = fmaxf(bi.x, bj.x), yy1 = fmaxf(bi.y, bj.y);
            float xx2 = fminf(bi.z, bj.z), yy2 = fminf(bi.w, bj.w);
            float inter = fmaxf(xx2 - xx1, 0.0f) * fmaxf(yy2 - yy1, 0.0f);
            float iou = inter / (ai + aj - inter + 1e-9f);  // EXACT ref arithmetic
            sup = iou > 0.7f;
        }
        u64 m = __ballot(sup);
        if (lane == 0) row[w] = m;
    }
}

// K5b: single-wave serial greedy reduce. Alive-test is a SCALAR bit-test on a
// readlane-refreshed current-word mask (no ds_bpermute on the serial chain);
// in-word updates come from the row's own word via readlane (depends only on
// the prefetch load, not on previous candidates). Rows: batch-16, double-buffered.
__global__ __launch_bounds__(64) void k_reduce(const float4* __restrict__ sboxes,
                                               const u64* __restrict__ M,
                                               const u64* __restrict__ irem,
                                               float* __restrict__ out) {
    __shared__ int kept[POST_NMS_N];
    int lane = threadIdx.x;
    u64 rem0 = irem[lane];                                  // word `lane`
    u64 rem1 = (lane < NWORDS - 64) ? irem[64 + lane] : ~0ull;  // word 64+lane
    int w1idx = (lane < NWORDS - 64) ? (64 + lane) : (NWORDS - 1);
    int w1real = 64 + lane;
    int kc = 0;
    bool done = false;
    int curw = -1;
    u64 curbits = ~0ull;

    u64 A0[16], A1[16], B0[16], B1[16];

#define LOADB(R0v, R1v, BASE)                                          \
    {                                                                  \
        _Pragma("unroll")                                              \
        for (int t = 0; t < 16; ++t) {                                 \
            int q = (BASE) + t;                                        \
            q = q < PRE_NMS_N ? q : (PRE_NMS_N - 1);                   \
            const u64* rp = M + (size_t)q * NWORDS;                    \
            R0v[t] = rp[lane];                                         \
            R1v[t] = rp[w1idx];                                        \
        }                                                              \
    }

#define PROCB(R0v, R1v, BASE)                                          \
    {                                                                  \
        _Pragma("unroll")                                              \
        for (int t = 0; t < 16; ++t) {                                 \
            int q = (BASE) + t;                                        \
            if (!done && q < PRE_NMS_N) {                              \
                int wq = q >> 6;                                       \
                if (wq != curw) {                                      \
                    curbits = (wq < 64) ? readlane_u64(rem0, wq)       \
                                        : readlane_u64(rem1, wq - 64); \
                    curw = wq;                                         \
                }                                                      \
                if (!((curbits >> (q & 63)) & 1ull)) {                 \
                    if (lane == 0) kept[kc] = q;                       \
                    ++kc;                                              \
                    u64 roww = (wq < 64)                               \
                        ? readlane_u64(R0v[t], wq)                     \
                        : readlane_u64(R1v[t], wq - 64);               \
                    curbits |= roww;                                   \
                    rem0 |= (lane >= wq) ? R0v[t] : 0ull;              \
                    rem1 |= (w1real >= wq) ? R1v[t] : 0ull;            \
                    if (kc >= POST_NMS_N) done = true;                 \
                }                                                      \
            }                                                          \
        }                                                              \
    }

    LOADB(A0, A1, 0);
    for (int base = 0; base < PRE_NMS_N; base += 32) {
        LOADB(B0, B1, base + 16);
        PROCB(A0, A1, base);
        if (done) break;
        LOADB(A0, A1, base + 32);
        PROCB(B0, B1, base + 16);
        if (done) break;
    }
#undef LOADB
#undef PROCB

    // lane0 wrote kept[]; single wave => in-order LDS visibility, no barrier
    for (int r = lane; r < POST_NMS_N; r += 64) {
        float4 v = make_float4(0.0f, 0.0f, 0.0f, 0.0f);
        if (r < kc) v = sboxes[kept[r]];
        ((float4*)out)[r] = v;
    }
}

// Fallback NMS (single fused kernel) if ws_size can't hold the bitmask matrix.
__global__ void k_nms(const float4* __restrict__ sboxes, float* __restrict__ out) {
    __shared__ float4 boxes[PRE_NMS_N];
    __shared__ u64 removed[NWORDS];
    __shared__ int kept[POST_NMS_N];
    int tid = threadIdx.x;
    int lane = tid & 63, wave = tid >> 6;

    for (int r = tid; r < PRE_NMS_N; r += 1024) boxes[r] = sboxes[r];
    __syncthreads();
    for (int r = tid; r < NWORDS * 64; r += 1024) {
        bool rm = true;
        if (r < PRE_NMS_N) {
            float4 b = boxes[r];
            rm = !((b.z - b.x >= 16.0f) && (b.w - b.y >= 16.0f));
        }
        u64 m = __ballot(rm);
        if (lane == 0) removed[r >> 6] = m;
    }
    __syncthreads();

    int kc = 0;
    int i = 0;
    while (i < PRE_NMS_N) {
        int w = i >> 6;
        u64 wd = removed[w] | ((1ull << (i & 63)) - 1ull);
        while (wd == ~0ull) {
            ++w;
            if (w >= NWORDS) break;
            wd = removed[w];
        }
        if (w >= NWORDS) break;
        i = (w << 6) + (__ffsll((u64)(~wd)) - 1);
        if (i >= PRE_NMS_N) break;

        if (tid == 0) kept[kc] = i;
        ++kc;
        if (kc >= POST_NMS_N) break;

        float4 bi = boxes[i];
        float area_i = (bi.z - bi.x) * (bi.w - bi.y);
        for (int c = (i >> 6) + wave; c < NWORDS; c += 16) {
            int j = (c << 6) + lane;
            bool sup = false;
            if (j > i && j < PRE_NMS_N) {
                float4 bj = boxes[j];
                float area_j = (bj.z - bj.x) * (bj.w - bj.y);
                float xx1 = fmaxf(bi.x, bj.x), yy1 = fmaxf(bi.y, bj.y);
                float xx2 = fminf(bi.z, bj.z), yy2 = fminf(bi.w, bj.w);
                float iw = fmaxf(xx2 - xx1, 0.0f), ih = fmaxf(yy2 - yy1, 0.0f);
                float inter = iw * ih;
                float iou = inter / (area_i + area_j - inter + 1e-9f);
                sup = iou > 0.7f;
            }
            u64 m = __ballot(sup);
            if (lane == 0 && m) removed[c] |= m;
        }
        __syncthreads();
        ++i;
    }
    __syncthreads();

    for (int r = tid; r < POST_NMS_N; r += 1024) {
        float4 v = make_float4(0.0f, 0.0f, 0.0f, 0.0f);
        if (r < kc) v = boxes[kept[r]];
        ((float4*)out)[r] = v;
    }
}

extern "C" void kernel_launch(void* const* d_in, const int* in_sizes, int n_in,
                              void* d_out, int out_size, void* d_ws, size_t ws_size,
                              hipStream_t stream) {
    const float4* anchors = (const float4*)d_in[0];
    const float*  cls     = (const float*)d_in[1];
    const float4* reg     = (const float4*)d_in[2];
    const int*    img_w   = (const int*)d_in[3];
    const int*    img_h   = (const int*)d_in[4];

    char* ws = (char*)d_ws;
    float4* bbox   = (float4*)(ws + OFF_BBOX);
    u64*    keys   = (u64*)   (ws + OFF_KEYS);
    u64*    gkeys  = (u64*)   (ws + OFF_GK);
    float4* sboxes = (float4*)(ws + OFF_SBOX);
    u32*    meta   = (u32*)   (ws + OFF_META);
    u32*    cnt    = (u32*)   (ws + OFF_CNT);
    u32*    offs   = (u32*)   (ws + OFF_OFFS);
    u64*    irem   = (u64*)   (ws + OFF_IREM);
    u64*    M      = (u64*)   (ws + OFF_M);

    k_decode <<<dim3((N_ANCH + 255) / 256), dim3(256), 0, stream>>>(
        anchors, cls, reg, img_w, img_h, bbox, keys);
    k_scan   <<<dim3(1), dim3(1024), 0, stream>>>(keys, offs, cnt, irem, meta);
    k_scatter<<<dim3((N_ANCH + 255) / 256), dim3(256), 0, stream>>>(
        keys, offs, cnt, gkeys, meta);
    k_rank   <<<dim3(GK_CAP / 256), dim3(256), 0, stream>>>(
        gkeys, offs, bbox, sboxes, irem, meta);

    if (ws_size >= WS_FULL) {
        k_iou    <<<dim3(PRE_NMS_N / 16), dim3(1024), 0, stream>>>(sboxes, M);
        k_reduce <<<dim3(1), dim3(64), 0, stream>>>(sboxes, M, irem, (float*)d_out);
    } else {
        k_nms    <<<dim3(1), dim3(1024), 0, stream>>>(sboxes, (float*)d_out);
    }
}